// Round 4
// baseline (156.392 us; speedup 1.0000x reference)
//
#include <hip/hip_runtime.h>
#include <hip/hip_bf16.h>
#include <cstdint>

using f32x4  = __attribute__((ext_vector_type(4))) float;
using bf16x8 = __attribute__((ext_vector_type(8))) short;
typedef unsigned short u16;

#define B_DIM 64
#define N_DIM 1024
#define P_DIM 256
#define NTILE 8            // N / 128
#define NUPPER 36          // NTILE*(NTILE+1)/2
#define NB_PREP 16384      // (B*N)/4
#define NB_GRAM 2304       // B * NUPPER  (divisible by 8 — bijective XCD swizzle)
#define BK 32              // K-step (8 steps over P=256)
#define LDS_STRIDE 40      // u16: 32 data + 8 pad -> 80B rows, 16B-aligned,
                           // read banks (20r+4s)%32 -> <=2-way

// RNE float->bf16
__device__ __forceinline__ u16 f2bf(float f) {
  uint32_t u = __float_as_uint(f);
  u += 0x7fffu + ((u >> 16) & 1u);
  return (u16)(u >> 16);
}

// ---------------------------------------------------------------------------
// Kernel 1: fused BCE partial + per-row sumsq + fp32->bf16 cast. (~HBM floor)
// ---------------------------------------------------------------------------
__global__ __launch_bounds__(256) void prep_kernel(
    const float* __restrict__ X, const float* __restrict__ T,
    u16* __restrict__ Xbf, float* __restrict__ sq,
    float* __restrict__ pb) {
  int tid  = threadIdx.x;
  int w    = tid >> 6, lane = tid & 63;
  size_t row = (size_t)blockIdx.x * 4 + w;
  const float4 xv = ((const float4*)(X + row * P_DIM))[lane];
  const float4 tv = ((const float4*)(T + row * P_DIM))[lane];
  float xs[4] = {xv.x, xv.y, xv.z, xv.w};
  float ts[4] = {tv.x, tv.y, tv.z, tv.w};
  float sqp = 0.f, bce = 0.f;
  ushort4 us;
  u16* up = (u16*)&us;
  #pragma unroll
  for (int i = 0; i < 4; ++i) {
    float x = xs[i];
    sqp += x * x;
    bce += fmaxf(x, 0.f) - x * ts[i] + __logf(1.f + __expf(-fabsf(x)));
    up[i] = f2bf(x);
  }
  ((ushort4*)(Xbf + row * P_DIM))[lane] = us;
  #pragma unroll
  for (int off = 32; off; off >>= 1) {
    sqp += __shfl_down(sqp, off);
    bce += __shfl_down(bce, off);
  }
  __shared__ float red[4];
  if (lane == 0) { sq[row] = sqp; red[w] = bce; }
  __syncthreads();
  if (tid == 0)
    pb[blockIdx.x] = red[0] + red[1] + red[2] + red[3];
}

// ---------------------------------------------------------------------------
// Kernel 2: 128x128 Gram tile via mfma 16x16x32 bf16.
// R4: reg-staged LDS fill — fully-coalesced global_load_dwordx4 -> VGPR
//     (issued BEFORE compute of current step; T14-lite) + ds_write_b128 to a
//     PADDED linear LDS (stride 40 u16) -> no 16B source scatter (R3 theory:
//     scattered 16B chunks rate-limited the memory path), no read conflicts.
//     BK=32 -> 8 steps, 20KB LDS, target 4 blocks/CU.
// ---------------------------------------------------------------------------
__global__ __launch_bounds__(256) void gram_kernel(
    const u16* __restrict__ Xbf, const float* __restrict__ sq,
    float* __restrict__ pd) {
  __shared__ __align__(16) u16 As[128 * LDS_STRIDE];
  __shared__ __align__(16) u16 Bs[128 * LDS_STRIDE];
  __shared__ float red[4];

  // XCD-aware swizzle (nwg % 8 == 0): XCD x gets batches [8x, 8x+8).
  int p   = blockIdx.x;
  int blk = (p & 7) * (NB_GRAM / 8) + (p >> 3);
  int b   = blk / NUPPER;
  int t   = blk - b * NUPPER;
  int TI  = 0;
  while (t >= NTILE - TI) { t -= NTILE - TI; ++TI; }
  int TJ = TI + t;                                // TJ >= TI
  const bool diag = (TI == TJ);

  const u16*   Xb  = Xbf + (size_t)b * N_DIM * P_DIM;
  const float* sqb = sq + b * N_DIM;

  int tid  = threadIdx.x;
  int lane = tid & 63;
  int w    = tid >> 6;
  int wr   = w >> 1, wc = w & 1;                  // 2x2 wave grid, 64x64 each
  const bool live = !(diag && wr > wc);

  f32x4 acc[4][4];
  #pragma unroll
  for (int m = 0; m < 4; ++m)
    #pragma unroll
    for (int n = 0; n < 4; ++n)
      acc[m][n] = (f32x4)(0.f);

  const int rowA = TI * 128, rowB = TJ * 128;

  // Per-thread staging: 2 A-chunks + 2 B-chunks of 16B per step.
  // chunk id = q*256+tid in [0,512): r = id>>2 (row 0..127), ch = id&3.
  uint4 ra[2], rb[2];
  const int sr = tid >> 2;            // staging row for q=0 (q=1: +64)
  const int sch = tid & 3;            // staging 16B chunk within 32-u16 row

  auto load_regs = [&](int k0) {
    #pragma unroll
    for (int q = 0; q < 2; ++q) {
      int r = sr + q * 64;
      const u16* ga = Xb + (size_t)(rowA + r) * P_DIM + k0 + sch * 8;
      ra[q] = *(const uint4*)ga;
      if (!diag) {
        const u16* gb = Xb + (size_t)(rowB + r) * P_DIM + k0 + sch * 8;
        rb[q] = *(const uint4*)gb;
      }
    }
  };
  auto write_lds = [&]() {
    #pragma unroll
    for (int q = 0; q < 2; ++q) {
      int r = sr + q * 64;
      *(uint4*)&As[r * LDS_STRIDE + sch * 8] = ra[q];
      if (!diag)
        *(uint4*)&Bs[r * LDS_STRIDE + sch * 8] = rb[q];
    }
  };

  // Prologue: fill step 0.
  load_regs(0);
  write_lds();
  __syncthreads();

  for (int step = 0; step < 8; ++step) {
    if (step < 7) load_regs((step + 1) * BK);   // flies under compute
    if (live) {
      const u16* Ab = As;
      const u16* Bb = diag ? As : Bs;
      int s = lane >> 4;                         // 8-elem K-slot 0..3
      bf16x8 bfg[4];
      #pragma unroll
      for (int n = 0; n < 4; ++n) {
        int r = wc * 64 + n * 16 + (lane & 15);
        bfg[n] = *(const bf16x8*)&Bb[r * LDS_STRIDE + s * 8];
      }
      #pragma unroll
      for (int m = 0; m < 4; ++m) {
        int r = wr * 64 + m * 16 + (lane & 15);
        bf16x8 af = *(const bf16x8*)&Ab[r * LDS_STRIDE + s * 8];
        #pragma unroll
        for (int n = 0; n < 4; ++n)
          acc[m][n] = __builtin_amdgcn_mfma_f32_16x16x32_bf16(
              af, bfg[n], acc[m][n], 0, 0, 0);
      }
    }
    __syncthreads();                 // all waves done reading this step's LDS
    if (step < 7) {
      write_lds();                   // compiler waits vmcnt for ra/rb
      __syncthreads();
    }
  }

  // Epilogue: C layout (m89/m91): col = lane&15, row = (lane>>4)*4 + v.
  float s = 0.f;
  if (live) {
    int rb2 = rowA + wr * 64, cb = rowB + wc * 64;
    #pragma unroll
    for (int m = 0; m < 4; ++m) {
      #pragma unroll
      for (int n = 0; n < 4; ++n) {
        #pragma unroll
        for (int v = 0; v < 4; ++v) {
          int gi = rb2 + m * 16 + (lane >> 4) * 4 + v;
          int gj = cb + n * 16 + (lane & 15);
          if (gi < gj) {
            float d2 = sqb[gi] + sqb[gj] - 2.f * acc[m][n][v];
            s += sqrtf(fmaxf(d2, 0.f));
          }
        }
      }
    }
  }
  #pragma unroll
  for (int off = 32; off; off >>= 1) s += __shfl_down(s, off);
  if (lane == 0) red[w] = s;
  __syncthreads();
  if (tid == 0)
    pd[blockIdx.x] = red[0] + red[1] + red[2] + red[3];
}

// ---------------------------------------------------------------------------
// Kernel 3: reduce partials (double) and combine.
// ---------------------------------------------------------------------------
__global__ __launch_bounds__(256) void finalize_kernel(
    const float* __restrict__ pb, const float* __restrict__ pd,
    float* __restrict__ out) {
  int tid = threadIdx.x;
  double s = 0.0, d = 0.0;
  for (int i = tid; i < NB_PREP; i += 256) s += (double)pb[i];
  for (int i = tid; i < NB_GRAM; i += 256) d += (double)pd[i];
  #pragma unroll
  for (int off = 32; off; off >>= 1) {
    s += __shfl_down(s, off);
    d += __shfl_down(d, off);
  }
  __shared__ double sb[4], db[4];
  int w = tid >> 6, lane = tid & 63;
  if (lane == 0) { sb[w] = s; db[w] = d; }
  __syncthreads();
  if (tid == 0) {
    double bce = (sb[0] + sb[1] + sb[2] + sb[3]) /
                 (double)((size_t)B_DIM * N_DIM * P_DIM);
    double reg = (db[0] + db[1] + db[2] + db[3]) / (double)N_DIM;
    out[0] = (float)(bce - reg);
  }
}

extern "C" void kernel_launch(void* const* d_in, const int* in_sizes, int n_in,
                              void* d_out, int out_size, void* d_ws, size_t ws_size,
                              hipStream_t stream) {
  const float* X = (const float*)d_in[0];
  const float* T = (const float*)d_in[1];
  float* out = (float*)d_out;

  float* pb  = (float*)d_ws;
  float* pd  = (float*)((char*)d_ws + (64 << 10));
  float* sq  = (float*)((char*)d_ws + (80 << 10));
  u16*   Xbf = (u16*)  ((char*)d_ws + (336 << 10));

  prep_kernel<<<NB_PREP, 256, 0, stream>>>(X, T, Xbf, sq, pb);
  gram_kernel<<<NB_GRAM, 256, 0, stream>>>(Xbf, sq, pd);
  finalize_kernel<<<1, 256, 0, stream>>>(pb, pd, out);
}

// Round 5
// 87.546 us; speedup vs baseline: 1.7864x; 1.7864x over previous
//
#include <hip/hip_runtime.h>
#include <hip/hip_bf16.h>
#include <cstdint>

using f32x4  = __attribute__((ext_vector_type(4))) float;
using bf16x8 = __attribute__((ext_vector_type(8))) short;
typedef unsigned short u16;

#define B_DIM 64
#define N_DIM 1024
#define P_DIM 256
#define NTILE 8            // N / 128
#define NUPPER 36          // NTILE*(NTILE+1)/2
#define NB_PREP 16384      // (B*N)/4
#define NB_GRAM 2304       // B * NUPPER  (divisible by 8 — bijective XCD swizzle)

// RNE float->bf16
__device__ __forceinline__ u16 f2bf(float f) {
  uint32_t u = __float_as_uint(f);
  u += 0x7fffu + ((u >> 16) & 1u);
  return (u16)(u >> 16);
}

// ---------------------------------------------------------------------------
// Kernel 1: fused BCE partial + per-row sumsq + fp32->bf16 cast. (~HBM floor)
// ---------------------------------------------------------------------------
__global__ __launch_bounds__(256) void prep_kernel(
    const float* __restrict__ X, const float* __restrict__ T,
    u16* __restrict__ Xbf, float* __restrict__ sq,
    float* __restrict__ pb) {
  int tid  = threadIdx.x;
  int w    = tid >> 6, lane = tid & 63;
  size_t row = (size_t)blockIdx.x * 4 + w;
  const float4 xv = ((const float4*)(X + row * P_DIM))[lane];
  const float4 tv = ((const float4*)(T + row * P_DIM))[lane];
  float xs[4] = {xv.x, xv.y, xv.z, xv.w};
  float ts[4] = {tv.x, tv.y, tv.z, tv.w};
  float sqp = 0.f, bce = 0.f;
  ushort4 us;
  u16* up = (u16*)&us;
  #pragma unroll
  for (int i = 0; i < 4; ++i) {
    float x = xs[i];
    sqp += x * x;
    bce += fmaxf(x, 0.f) - x * ts[i] + __logf(1.f + __expf(-fabsf(x)));
    up[i] = f2bf(x);
  }
  ((ushort4*)(Xbf + row * P_DIM))[lane] = us;
  #pragma unroll
  for (int off = 32; off; off >>= 1) {
    sqp += __shfl_down(sqp, off);
    bce += __shfl_down(bce, off);
  }
  __shared__ float red[4];
  if (lane == 0) { sq[row] = sqp; red[w] = bce; }
  __syncthreads();
  if (tid == 0)
    pb[blockIdx.x] = red[0] + red[1] + red[2] + red[3];
}

// ---------------------------------------------------------------------------
// Kernel 2: 128x128 Gram tile via mfma 16x16x32 bf16 — m97-pure structure:
// CONTIGUOUS global_load_lds source (8x128B segments per wave), LINEAR LDS
// [128][64], single buffer (32KB -> ~4 blocks/CU), drain-before-compute per
// K-step; inter-block wave overlap hides the drain (m114). No swizzle
// anywhere (R2/R3's scattered-16B source was the request-rate killer theory).
// Keeps: XCD swizzle (FETCH 118->17MB proven), diag specialization, and adds
// register prefetch of sq for the epilogue.
// ---------------------------------------------------------------------------
__global__ __launch_bounds__(256) void gram_kernel(
    const u16* __restrict__ Xbf, const float* __restrict__ sq,
    float* __restrict__ pd) {
  __shared__ u16 As[128 * 64];
  __shared__ u16 Bs[128 * 64];
  __shared__ float red[4];

  // XCD-aware swizzle (nwg % 8 == 0): XCD x gets batches [8x, 8x+8).
  int p   = blockIdx.x;
  int blk = (p & 7) * (NB_GRAM / 8) + (p >> 3);
  int b   = blk / NUPPER;
  int t   = blk - b * NUPPER;
  int TI  = 0;
  while (t >= NTILE - TI) { t -= NTILE - TI; ++TI; }
  int TJ = TI + t;                                // TJ >= TI
  const bool diag = (TI == TJ);

  const u16*   Xb  = Xbf + (size_t)b * N_DIM * P_DIM;
  const float* sqb = sq + b * N_DIM;

  int tid  = threadIdx.x;
  int lane = tid & 63;
  int w    = tid >> 6;
  int wr   = w >> 1, wc = w & 1;                  // 2x2 wave grid, 64x64 each
  const bool live = !(diag && wr > wc);

  const int rowA = TI * 128, rowB = TJ * 128;

  // Prefetch epilogue sq values into registers (L2-hit; overlaps K-loop).
  float sqa[16], sqc[4];
  {
    int rb2 = rowA + wr * 64 + (lane >> 4) * 4;
    int cb  = rowB + wc * 64 + (lane & 15);
    #pragma unroll
    for (int m = 0; m < 4; ++m)
      #pragma unroll
      for (int v = 0; v < 4; ++v)
        sqa[m * 4 + v] = sqb[rb2 + m * 16 + v];
    #pragma unroll
    for (int n = 0; n < 4; ++n)
      sqc[n] = sqb[cb + n * 16];
  }

  f32x4 acc[4][4];
  #pragma unroll
  for (int m = 0; m < 4; ++m)
    #pragma unroll
    for (int n = 0; n < 4; ++n)
      acc[m][n] = (f32x4)(0.f);

  for (int step = 0; step < 4; ++step) {
    int k0 = step * 64;
    if (step) __syncthreads();                    // done reading prev tiles
    // Contiguous staging: chunk idx -> row r = idx>>3, 16B slot idx&7.
    // Wave covers 8 rows x 128B contiguous each; LDS dest = base + lane*16.
    #pragma unroll
    for (int q = 0; q < 4; ++q) {
      int idx = q * 256 + tid;
      int r   = idx >> 3;
      const u16* ga = Xb + (size_t)(rowA + r) * P_DIM + k0 + (idx & 7) * 8;
      __builtin_amdgcn_global_load_lds(
          (const __attribute__((address_space(1))) void*)ga,
          (__attribute__((address_space(3))) void*)(&As[idx * 8]), 16, 0, 0);
      if (!diag) {
        const u16* gb = Xb + (size_t)(rowB + r) * P_DIM + k0 + (idx & 7) * 8;
        __builtin_amdgcn_global_load_lds(
            (const __attribute__((address_space(1))) void*)gb,
            (__attribute__((address_space(3))) void*)(&Bs[idx * 8]), 16, 0, 0);
      }
    }
    asm volatile("s_waitcnt vmcnt(0)" ::: "memory");
    __syncthreads();
    if (live) {
      const u16* Ab = As;
      const u16* Bb = diag ? As : Bs;
      #pragma unroll
      for (int kk = 0; kk < 64; kk += 32) {
        bf16x8 af[4], bfg[4];
        int s = (kk >> 3) + (lane >> 4);          // 16B slot within row, 0..7
        #pragma unroll
        for (int m = 0; m < 4; ++m) {
          int r = wr * 64 + m * 16 + (lane & 15);
          af[m] = *(const bf16x8*)&Ab[r * 64 + s * 8];
        }
        #pragma unroll
        for (int n = 0; n < 4; ++n) {
          int r = wc * 64 + n * 16 + (lane & 15);
          bfg[n] = *(const bf16x8*)&Bb[r * 64 + s * 8];
        }
        #pragma unroll
        for (int m = 0; m < 4; ++m)
          #pragma unroll
          for (int n = 0; n < 4; ++n)
            acc[m][n] = __builtin_amdgcn_mfma_f32_16x16x32_bf16(
                af[m], bfg[n], acc[m][n], 0, 0, 0);
      }
    }
  }

  // Epilogue: C layout (m89/m91): col = lane&15, row = (lane>>4)*4 + v.
  float s = 0.f;
  if (live) {
    int rb2 = rowA + wr * 64, cb = rowB + wc * 64;
    #pragma unroll
    for (int m = 0; m < 4; ++m) {
      #pragma unroll
      for (int n = 0; n < 4; ++n) {
        #pragma unroll
        for (int v = 0; v < 4; ++v) {
          int gi = rb2 + m * 16 + (lane >> 4) * 4 + v;
          int gj = cb + n * 16 + (lane & 15);
          if (gi < gj) {
            float d2 = sqa[m * 4 + v] + sqc[n] - 2.f * acc[m][n][v];
            s += sqrtf(fmaxf(d2, 0.f));
          }
        }
      }
    }
  }
  #pragma unroll
  for (int off = 32; off; off >>= 1) s += __shfl_down(s, off);
  __syncthreads();                                // K-loop's last read done
  if (lane == 0) red[w] = s;
  __syncthreads();
  if (tid == 0)
    pd[blockIdx.x] = red[0] + red[1] + red[2] + red[3];
}

// ---------------------------------------------------------------------------
// Kernel 3: reduce partials (double) and combine.
// ---------------------------------------------------------------------------
__global__ __launch_bounds__(256) void finalize_kernel(
    const float* __restrict__ pb, const float* __restrict__ pd,
    float* __restrict__ out) {
  int tid = threadIdx.x;
  double s = 0.0, d = 0.0;
  for (int i = tid; i < NB_PREP; i += 256) s += (double)pb[i];
  for (int i = tid; i < NB_GRAM; i += 256) d += (double)pd[i];
  #pragma unroll
  for (int off = 32; off; off >>= 1) {
    s += __shfl_down(s, off);
    d += __shfl_down(d, off);
  }
  __shared__ double sb[4], db[4];
  int w = tid >> 6, lane = tid & 63;
  if (lane == 0) { sb[w] = s; db[w] = d; }
  __syncthreads();
  if (tid == 0) {
    double bce = (sb[0] + sb[1] + sb[2] + sb[3]) /
                 (double)((size_t)B_DIM * N_DIM * P_DIM);
    double reg = (db[0] + db[1] + db[2] + db[3]) / (double)N_DIM;
    out[0] = (float)(bce - reg);
  }
}

extern "C" void kernel_launch(void* const* d_in, const int* in_sizes, int n_in,
                              void* d_out, int out_size, void* d_ws, size_t ws_size,
                              hipStream_t stream) {
  const float* X = (const float*)d_in[0];
  const float* T = (const float*)d_in[1];
  float* out = (float*)d_out;

  float* pb  = (float*)d_ws;
  float* pd  = (float*)((char*)d_ws + (64 << 10));
  float* sq  = (float*)((char*)d_ws + (80 << 10));
  u16*   Xbf = (u16*)  ((char*)d_ws + (336 << 10));

  prep_kernel<<<NB_PREP, 256, 0, stream>>>(X, T, Xbf, sq, pb);
  gram_kernel<<<NB_GRAM, 256, 0, stream>>>(Xbf, sq, pd);
  finalize_kernel<<<1, 256, 0, stream>>>(pb, pd, out);
}